// Round 5
// baseline (693.476 us; speedup 1.0000x reference)
//
#include <hip/hip_runtime.h>

// ---------------------------------------------------------------------------
// GCN forward: CSR aggregation with XCD-pinned feature-chunk blocking.
//   F split into 8 chunks (CHW=ceil(F/8)); chunk = blockIdx.x & 7 so, under
//   round-robin block->XCD dispatch, each chunk's 2.6MB H-slice stays resident
//   in ONE XCD's L2. Edge stream (packed (col,norm) int64) + A-writes use
//   non-temporal load/store so they don't evict the slice. 8-deep gather
//   unroll for MLP against ~200cyc L2 latency. No atomics in hot paths.
// ---------------------------------------------------------------------------

#define BT 256
#define SCAN_B 256

// ---------------- precompute ----------------
__global__ void init_kernel(int* counts, float* wsum, int n) {
    int i = blockIdx.x * blockDim.x + threadIdx.x;
    if (i < n) { counts[i] = 0; wsum[i] = 1.0f; }  // self-loop weight = 1
}

__global__ void hist_kernel(const int* __restrict__ row, const float* __restrict__ w,
                            int* counts, float* wsum, int e) {
    int i = blockIdx.x * blockDim.x + threadIdx.x;
    if (i < e) {
        int r = row[i];
        atomicAdd(&counts[r], 1);
        unsafeAtomicAdd(&wsum[r], w[i]);
    }
}

// exclusive scan of counts (in rowptr[0..n-1]); also wsum -> dis in-place
__global__ void scan1_kernel(int* counts, int* bsums, float* deg, int n) {
    __shared__ int s[SCAN_B];
    int t = threadIdx.x;
    int i = blockIdx.x * SCAN_B + t;
    int v = (i < n) ? counts[i] : 0;
    s[t] = v;
    __syncthreads();
    for (int off = 1; off < SCAN_B; off <<= 1) {
        int x = (t >= off) ? s[t - off] : 0;
        __syncthreads();
        s[t] += x;
        __syncthreads();
    }
    if (i < n) {
        counts[i] = s[t] - v;  // exclusive
        float d = deg[i];
        deg[i] = (d > 0.f) ? rsqrtf(fmaxf(d, 1e-12f)) : 0.f;
    }
    if (t == SCAN_B - 1) bsums[blockIdx.x] = s[t];
}

__global__ void scan2_kernel(int* bsums, int nb) {  // single block, nb <= SCAN_B
    __shared__ int s[SCAN_B];
    int t = threadIdx.x;
    int v = (t < nb) ? bsums[t] : 0;
    s[t] = v;
    __syncthreads();
    for (int off = 1; off < SCAN_B; off <<= 1) {
        int x = (t >= off) ? s[t - off] : 0;
        __syncthreads();
        s[t] += x;
        __syncthreads();
    }
    if (t < nb) bsums[t] = s[t] - v;
}

__global__ void scan3_kernel(int* rowptr, const int* __restrict__ bsums, int* cursor,
                             int n, int e) {
    int i = blockIdx.x * blockDim.x + threadIdx.x;
    if (i < n) {
        int rp = rowptr[i] + bsums[i / SCAN_B];
        rowptr[i] = rp;
        cursor[i] = rp;
    }
    if (i == 0) rowptr[n] = e;
}

__global__ void fill_kernel(const int* __restrict__ row, const int* __restrict__ col,
                            const float* __restrict__ w, const float* __restrict__ dis,
                            int* cursor, long long* __restrict__ epack, int e) {
    int i = blockIdx.x * blockDim.x + threadIdx.x;
    if (i >= e) return;
    int r = row[i], c = col[i];
    float nv = dis[r] * w[i] * dis[c];
    int dst = atomicAdd(&cursor[r], 1);
    long long v = ((long long)__float_as_int(nv) << 32) | (unsigned int)c;
    __builtin_nontemporal_store(v, &epack[dst]);
}

// ---------------- register-tiled GEMM: Hc = chunked(actin(X) @ W) ------------
// X row-major [n,K] (K%4==0); output chunked Hc[f/CHW][n][f%CHW], 8 chunks.
template <int K, int F, int CHW, bool RELU_IN>
__global__ __launch_bounds__(256) void gemm_tile_kernel(const float* __restrict__ X,
                                                        const float* __restrict__ W,
                                                        float* __restrict__ Hc, int n) {
    static_assert(K % 4 == 0, "K must be multiple of 4");
    constexpr int NCG = (F + 3) / 4;
    constexpr int FP = NCG * 4;
    constexpr int RG = 256 / NCG;
    constexpr int ROWS = RG * 4;

    __shared__ float Ws[K * FP];
    const int tid = threadIdx.x;
    for (int i = tid; i < K * FP; i += 256) {
        int k = i / FP, c = i - k * FP;
        Ws[i] = (c < F) ? W[k * F + c] : 0.f;
    }
    __syncthreads();

    const int txc = tid % NCG;
    const int tyr = tid / NCG;
    if (tyr >= RG) return;

    const int r0 = blockIdx.x * ROWS + tyr * 4;
    bool rv[4];
    const float* xrow[4];
#pragma unroll
    for (int i = 0; i < 4; ++i) {
        int r = r0 + i;
        rv[i] = (r < n);
        xrow[i] = X + (long long)(rv[i] ? r : 0) * K;
    }

    float acc[4][4] = {};
    const float* wbase = &Ws[txc * 4];
    for (int k = 0; k < K; k += 4) {
        float4 w0 = *reinterpret_cast<const float4*>(wbase + (k + 0) * FP);
        float4 w1 = *reinterpret_cast<const float4*>(wbase + (k + 1) * FP);
        float4 w2 = *reinterpret_cast<const float4*>(wbase + (k + 2) * FP);
        float4 w3 = *reinterpret_cast<const float4*>(wbase + (k + 3) * FP);
#pragma unroll
        for (int i = 0; i < 4; ++i) {
            float4 x4 = *reinterpret_cast<const float4*>(xrow[i] + k);
            if (RELU_IN) {
                x4.x = fmaxf(x4.x, 0.f); x4.y = fmaxf(x4.y, 0.f);
                x4.z = fmaxf(x4.z, 0.f); x4.w = fmaxf(x4.w, 0.f);
            }
            acc[i][0] += x4.x * w0.x + x4.y * w1.x + x4.z * w2.x + x4.w * w3.x;
            acc[i][1] += x4.x * w0.y + x4.y * w1.y + x4.z * w2.y + x4.w * w3.y;
            acc[i][2] += x4.x * w0.z + x4.y * w1.z + x4.z * w2.z + x4.w * w3.z;
            acc[i][3] += x4.x * w0.w + x4.y * w1.w + x4.z * w2.w + x4.w * w3.w;
        }
    }

#pragma unroll
    for (int i = 0; i < 4; ++i) {
        if (!rv[i]) continue;
        long long r = r0 + i;
#pragma unroll
        for (int j = 0; j < 4; ++j) {
            int c = txc * 4 + j;
            if (c < F) {
                int ch = c / CHW;
                int off = c - ch * CHW;
                Hc[(size_t)ch * n * CHW + r * CHW + off] = acc[i][j];
            }
        }
    }
}

// thread-per-row GEMV for tiny F (layer 3: K=50, F=6), row-major output.
template <int K, int F, bool RELU_IN>
__global__ __launch_bounds__(256) void gemv_rows_kernel(const float* __restrict__ X,
                                                        const float* __restrict__ W,
                                                        float* __restrict__ H, int n) {
    static_assert(K % 2 == 0, "K must be even");
    __shared__ float Ws[K * F];
    const int tid = threadIdx.x;
    for (int i = tid; i < K * F; i += 256) Ws[i] = W[i];
    __syncthreads();
    int r = blockIdx.x * 256 + tid;
    if (r >= n) return;
    float acc[F] = {};
    const float* xp = X + (long long)r * K;
    for (int k = 0; k < K; k += 2) {
        float2 x2 = *reinterpret_cast<const float2*>(xp + k);
        if (RELU_IN) { x2.x = fmaxf(x2.x, 0.f); x2.y = fmaxf(x2.y, 0.f); }
#pragma unroll
        for (int j = 0; j < F; ++j)
            acc[j] += x2.x * Ws[k * F + j] + x2.y * Ws[(k + 1) * F + j];
    }
    long long base = (long long)r * F;
#pragma unroll
    for (int j = 0; j < F; ++j) H[base + j] = acc[j];
}

// ---------------- XCD-pinned chunked CSR aggregation ----------------
// grid.x = 8 * ceil(n/NPB); chunk = blockIdx.x & 7 (-> pinned XCD under
// round-robin dispatch); segment of TPN lanes per node, lane = feature offset.
template <int F, int CHW, int TPN>
__global__ __launch_bounds__(BT) void agg_xcd_kernel(const int* __restrict__ rowptr,
                                                     const long long* __restrict__ epack,
                                                     const float* __restrict__ H,
                                                     const float* __restrict__ dis,
                                                     const float* __restrict__ bias,
                                                     float* __restrict__ A, int n) {
    constexpr int NPB = BT / TPN;  // nodes per block
    const int chunk = blockIdx.x & 7;
    const int nblk = blockIdx.x >> 3;
    const int tid = threadIdx.x;
    const int node = nblk * NPB + tid / TPN;
    const int lane = tid & (TPN - 1);
    if (node >= n) return;
    const float* __restrict__ Hc = H + (size_t)chunk * n * CHW;
    const int f = chunk * CHW + lane;
    const bool fv = (lane < CHW) && (f < F);

    float acc = 0.f;
    const int beg = rowptr[node], end = rowptr[node + 1];
    for (int base = beg; base < end; base += TPN) {
        int m = end - base;
        if (m > TPN) m = TPN;
        long long ev = 0;
        if (lane < m) ev = __builtin_nontemporal_load(epack + base + lane);
        int myc = (int)ev;
        float myn = __int_as_float((int)(ev >> 32));
        int j = 0;
        for (; j + 8 <= m; j += 8) {
            int c0 = __shfl(myc, j + 0, TPN); float n0 = __shfl(myn, j + 0, TPN);
            int c1 = __shfl(myc, j + 1, TPN); float n1 = __shfl(myn, j + 1, TPN);
            int c2 = __shfl(myc, j + 2, TPN); float n2 = __shfl(myn, j + 2, TPN);
            int c3 = __shfl(myc, j + 3, TPN); float n3 = __shfl(myn, j + 3, TPN);
            int c4 = __shfl(myc, j + 4, TPN); float n4 = __shfl(myn, j + 4, TPN);
            int c5 = __shfl(myc, j + 5, TPN); float n5 = __shfl(myn, j + 5, TPN);
            int c6 = __shfl(myc, j + 6, TPN); float n6 = __shfl(myn, j + 6, TPN);
            int c7 = __shfl(myc, j + 7, TPN); float n7 = __shfl(myn, j + 7, TPN);
            if (fv) {
                float h0 = Hc[(size_t)c0 * CHW + lane];
                float h1 = Hc[(size_t)c1 * CHW + lane];
                float h2 = Hc[(size_t)c2 * CHW + lane];
                float h3 = Hc[(size_t)c3 * CHW + lane];
                float h4 = Hc[(size_t)c4 * CHW + lane];
                float h5 = Hc[(size_t)c5 * CHW + lane];
                float h6 = Hc[(size_t)c6 * CHW + lane];
                float h7 = Hc[(size_t)c7 * CHW + lane];
                acc += n0 * h0 + n1 * h1;
                acc += n2 * h2 + n3 * h3;
                acc += n4 * h4 + n5 * h5;
                acc += n6 * h6 + n7 * h7;
            }
        }
        for (; j < m; ++j) {
            int c = __shfl(myc, j, TPN);
            float nv = __shfl(myn, j, TPN);
            if (fv) acc += nv * Hc[(size_t)c * CHW + lane];
        }
    }
    if (fv) {
        float d = dis[node];
        float v = bias[f] + d * d * Hc[(size_t)node * CHW + lane] + acc;
        __builtin_nontemporal_store(v, &A[(size_t)node * F + f]);
    }
}

// simple per-node agg for tiny F (row-major H, fully cache-resident)
template <int F, int TPN>
__global__ __launch_bounds__(BT) void agg_small_kernel(const int* __restrict__ rowptr,
                                                       const long long* __restrict__ epack,
                                                       const float* __restrict__ H,
                                                       const float* __restrict__ dis,
                                                       const float* __restrict__ bias,
                                                       float* __restrict__ A, int n) {
    int gid = blockIdx.x * blockDim.x + threadIdx.x;
    int node = gid / TPN;
    int lane = threadIdx.x & (TPN - 1);
    if (node >= n) return;
    bool active = (lane < F);
    float acc = 0.f;
    int beg = rowptr[node], end = rowptr[node + 1];
    for (int e = beg; e < end; ++e) {
        long long ev = __builtin_nontemporal_load(epack + e);
        int c = (int)ev;
        float nv = __int_as_float((int)(ev >> 32));
        if (active) acc += nv * H[(size_t)c * F + lane];
    }
    if (active) {
        float d = dis[node];
        float v = bias[lane] + d * d * H[(size_t)node * F + lane] + acc;
        __builtin_nontemporal_store(v, &A[(size_t)node * F + lane]);
    }
}

// ---------------------------------------------------------------------------
extern "C" void kernel_launch(void* const* d_in, const int* in_sizes, int n_in,
                              void* d_out, int out_size, void* d_ws, size_t ws_size,
                              hipStream_t stream) {
    const float* x  = (const float*)d_in[0];
    const int*   ei = (const int*)d_in[1];
    const float* ew = (const float*)d_in[2];
    const float* W0 = (const float*)d_in[3];
    const float* b0 = (const float*)d_in[4];
    const float* W1 = (const float*)d_in[5];
    const float* b1 = (const float*)d_in[6];
    const float* W2 = (const float*)d_in[7];
    const float* b2 = (const float*)d_in[8];
    const float* W3 = (const float*)d_in[9];
    const float* b3 = (const float*)d_in[10];
    float* out = (float*)d_out;

    const int N = in_sizes[0] / 128;  // 50000
    const int E = in_sizes[1] / 2;    // 800000
    const int* row = ei;
    const int* col = ei + E;

    const int NB = (N + SCAN_B - 1) / SCAN_B;

    // workspace (8B alignment maintained for epack):
    // dis[N] f | rowptr[N+2] i | cursor[N] i | bsums[SCAN_B] i |
    // epack[E] i64 | bufA[N*104] f (chunk-padded H) | bufB[N*100] f
    float* ws = (float*)d_ws;
    float* dis    = ws;
    int*   rowptr = (int*)(dis + N);
    int*   cursor = rowptr + (N + 2);
    int*   bsums  = cursor + N;
    long long* epack = (long long*)(bsums + SCAN_B);
    float* bufA   = (float*)(epack + E);
    float* bufB   = bufA + (size_t)N * 104;

    // ---- CSR + norm precompute ----
    init_kernel<<<(N + BT - 1) / BT, BT, 0, stream>>>(rowptr, dis, N);
    hist_kernel<<<(E + BT - 1) / BT, BT, 0, stream>>>(row, ew, rowptr, dis, E);
    scan1_kernel<<<NB, SCAN_B, 0, stream>>>(rowptr, bsums, dis, N);
    scan2_kernel<<<1, SCAN_B, 0, stream>>>(bsums, NB);
    scan3_kernel<<<(N + BT - 1) / BT, BT, 0, stream>>>(rowptr, bsums, cursor, N, E);
    fill_kernel<<<(E + BT - 1) / BT, BT, 0, stream>>>(row, col, ew, dis, cursor, epack, E);

    // GEMM rows/block: F=100 -> NCG=25, ROWS=40; F=50 -> NCG=13, ROWS=76
    const int g100_blocks = (N + 39) / 40;
    const int g50_blocks  = (N + 75) / 76;

    // agg grids: 8 chunks x node-blocks
    const int agg100_blocks = 8 * ((N + 15) / 16);  // CHW=13, TPN=16, NPB=16
    const int agg50_blocks  = 8 * ((N + 31) / 32);  // CHW=7,  TPN=8,  NPB=32
    const int agg6_blocks   = (N * 8 + BT - 1) / BT;

    // ---- layer 0: x(128) -> 100 ----
    gemm_tile_kernel<128, 100, 13, false><<<g100_blocks, 256, 0, stream>>>(x, W0, bufA, N);
    agg_xcd_kernel<100, 13, 16><<<agg100_blocks, BT, 0, stream>>>(rowptr, epack, bufA, dis, b0, bufB, N);

    // ---- layer 1: 100 -> 100 ----
    gemm_tile_kernel<100, 100, 13, true><<<g100_blocks, 256, 0, stream>>>(bufB, W1, bufA, N);
    agg_xcd_kernel<100, 13, 16><<<agg100_blocks, BT, 0, stream>>>(rowptr, epack, bufA, dis, b1, bufB, N);

    // ---- layer 2: 100 -> 50 ----
    gemm_tile_kernel<100, 50, 7, true><<<g50_blocks, 256, 0, stream>>>(bufB, W2, bufA, N);
    agg_xcd_kernel<50, 7, 8><<<agg50_blocks, BT, 0, stream>>>(rowptr, epack, bufA, dis, b2, bufB, N);

    // ---- layer 3: 50 -> 6 ----
    gemv_rows_kernel<50, 6, true><<<(N + 255) / 256, 256, 0, stream>>>(bufB, W3, bufA, N);
    agg_small_kernel<6, 8><<<agg6_blocks, BT, 0, stream>>>(rowptr, epack, bufA, dis, b3, out, N);
}

// Round 6
// 600.805 us; speedup vs baseline: 1.1542x; 1.1542x over previous
//
#include <hip/hip_runtime.h>

// ---------------------------------------------------------------------------
// GCN forward: CSR aggregation, XCD-pinned feature chunks + broadcast loads.
//   F split into 8 chunks (CHW=ceil(F/8)); chunk = blockIdx.x & 7 so under
//   round-robin block->XCD dispatch each chunk's H-slice stays resident in ONE
//   XCD's L2 (R5: FETCH 133->45MB). Edge metadata distributed to segment lanes
//   via SAME-ADDRESS loads (HW broadcast, L1-cached, 8 edges/line) instead of
//   __shfl chains (R5's serializing critical path). 8-deep unrolled gathers.
//   A-stores nontemporal; everything else cached. No atomics in hot paths.
// ---------------------------------------------------------------------------

#define BT 256
#define SCAN_B 256

// ---------------- precompute ----------------
__global__ void init_kernel(int* counts, float* wsum, int n) {
    int i = blockIdx.x * blockDim.x + threadIdx.x;
    if (i < n) { counts[i] = 0; wsum[i] = 1.0f; }  // self-loop weight = 1
}

__global__ void hist_kernel(const int* __restrict__ row, const float* __restrict__ w,
                            int* counts, float* wsum, int e) {
    int i = blockIdx.x * blockDim.x + threadIdx.x;
    if (i < e) {
        int r = row[i];
        atomicAdd(&counts[r], 1);
        unsafeAtomicAdd(&wsum[r], w[i]);
    }
}

// exclusive scan of counts (in rowptr[0..n-1]); also wsum -> dis in-place
__global__ void scan1_kernel(int* counts, int* bsums, float* deg, int n) {
    __shared__ int s[SCAN_B];
    int t = threadIdx.x;
    int i = blockIdx.x * SCAN_B + t;
    int v = (i < n) ? counts[i] : 0;
    s[t] = v;
    __syncthreads();
    for (int off = 1; off < SCAN_B; off <<= 1) {
        int x = (t >= off) ? s[t - off] : 0;
        __syncthreads();
        s[t] += x;
        __syncthreads();
    }
    if (i < n) {
        counts[i] = s[t] - v;  // exclusive
        float d = deg[i];
        deg[i] = (d > 0.f) ? rsqrtf(fmaxf(d, 1e-12f)) : 0.f;
    }
    if (t == SCAN_B - 1) bsums[blockIdx.x] = s[t];
}

__global__ void scan2_kernel(int* bsums, int nb) {  // single block, nb <= SCAN_B
    __shared__ int s[SCAN_B];
    int t = threadIdx.x;
    int v = (t < nb) ? bsums[t] : 0;
    s[t] = v;
    __syncthreads();
    for (int off = 1; off < SCAN_B; off <<= 1) {
        int x = (t >= off) ? s[t - off] : 0;
        __syncthreads();
        s[t] += x;
        __syncthreads();
    }
    if (t < nb) bsums[t] = s[t] - v;
}

__global__ void scan3_kernel(int* rowptr, const int* __restrict__ bsums, int* cursor,
                             int n, int e) {
    int i = blockIdx.x * blockDim.x + threadIdx.x;
    if (i < n) {
        int rp = rowptr[i] + bsums[i / SCAN_B];
        rowptr[i] = rp;
        cursor[i] = rp;
    }
    if (i == 0) rowptr[n] = e;
}

__global__ void fill_kernel(const int* __restrict__ row, const int* __restrict__ col,
                            const float* __restrict__ w, const float* __restrict__ dis,
                            int* cursor, long long* __restrict__ epack, int e) {
    int i = blockIdx.x * blockDim.x + threadIdx.x;
    if (i >= e) return;
    int r = row[i], c = col[i];
    float nv = dis[r] * w[i] * dis[c];
    int dst = atomicAdd(&cursor[r], 1);
    long long v = ((long long)__float_as_int(nv) << 32) | (unsigned int)c;
    __builtin_nontemporal_store(v, &epack[dst]);
}

// ---------------- register-tiled GEMM: Hc = chunked(actin(X) @ W) ------------
// X row-major [n,K] (K%4==0); output chunked Hc[f/CHW][n][f%CHW], 8 chunks.
template <int K, int F, int CHW, bool RELU_IN>
__global__ __launch_bounds__(256) void gemm_tile_kernel(const float* __restrict__ X,
                                                        const float* __restrict__ W,
                                                        float* __restrict__ Hc, int n) {
    static_assert(K % 4 == 0, "K must be multiple of 4");
    constexpr int NCG = (F + 3) / 4;
    constexpr int FP = NCG * 4;
    constexpr int RG = 256 / NCG;
    constexpr int ROWS = RG * 4;

    __shared__ float Ws[K * FP];
    const int tid = threadIdx.x;
    for (int i = tid; i < K * FP; i += 256) {
        int k = i / FP, c = i - k * FP;
        Ws[i] = (c < F) ? W[k * F + c] : 0.f;
    }
    __syncthreads();

    const int txc = tid % NCG;
    const int tyr = tid / NCG;
    if (tyr >= RG) return;

    const int r0 = blockIdx.x * ROWS + tyr * 4;
    bool rv[4];
    const float* xrow[4];
#pragma unroll
    for (int i = 0; i < 4; ++i) {
        int r = r0 + i;
        rv[i] = (r < n);
        xrow[i] = X + (long long)(rv[i] ? r : 0) * K;
    }

    float acc[4][4] = {};
    const float* wbase = &Ws[txc * 4];
    for (int k = 0; k < K; k += 4) {
        float4 w0 = *reinterpret_cast<const float4*>(wbase + (k + 0) * FP);
        float4 w1 = *reinterpret_cast<const float4*>(wbase + (k + 1) * FP);
        float4 w2 = *reinterpret_cast<const float4*>(wbase + (k + 2) * FP);
        float4 w3 = *reinterpret_cast<const float4*>(wbase + (k + 3) * FP);
#pragma unroll
        for (int i = 0; i < 4; ++i) {
            float4 x4 = *reinterpret_cast<const float4*>(xrow[i] + k);
            if (RELU_IN) {
                x4.x = fmaxf(x4.x, 0.f); x4.y = fmaxf(x4.y, 0.f);
                x4.z = fmaxf(x4.z, 0.f); x4.w = fmaxf(x4.w, 0.f);
            }
            acc[i][0] += x4.x * w0.x + x4.y * w1.x + x4.z * w2.x + x4.w * w3.x;
            acc[i][1] += x4.x * w0.y + x4.y * w1.y + x4.z * w2.y + x4.w * w3.y;
            acc[i][2] += x4.x * w0.z + x4.y * w1.z + x4.z * w2.z + x4.w * w3.z;
            acc[i][3] += x4.x * w0.w + x4.y * w1.w + x4.z * w2.w + x4.w * w3.w;
        }
    }

#pragma unroll
    for (int i = 0; i < 4; ++i) {
        if (!rv[i]) continue;
        long long r = r0 + i;
#pragma unroll
        for (int j = 0; j < 4; ++j) {
            int c = txc * 4 + j;
            if (c < F) {
                int ch = c / CHW;
                int off = c - ch * CHW;
                Hc[(size_t)ch * n * CHW + r * CHW + off] = acc[i][j];
            }
        }
    }
}

// thread-per-row GEMV for tiny F (layer 3: K=50, F=6), row-major output.
template <int K, int F, bool RELU_IN>
__global__ __launch_bounds__(256) void gemv_rows_kernel(const float* __restrict__ X,
                                                        const float* __restrict__ W,
                                                        float* __restrict__ H, int n) {
    static_assert(K % 2 == 0, "K must be even");
    __shared__ float Ws[K * F];
    const int tid = threadIdx.x;
    for (int i = tid; i < K * F; i += 256) Ws[i] = W[i];
    __syncthreads();
    int r = blockIdx.x * 256 + tid;
    if (r >= n) return;
    float acc[F] = {};
    const float* xp = X + (long long)r * K;
    for (int k = 0; k < K; k += 2) {
        float2 x2 = *reinterpret_cast<const float2*>(xp + k);
        if (RELU_IN) { x2.x = fmaxf(x2.x, 0.f); x2.y = fmaxf(x2.y, 0.f); }
#pragma unroll
        for (int j = 0; j < F; ++j)
            acc[j] += x2.x * Ws[k * F + j] + x2.y * Ws[(k + 1) * F + j];
    }
    long long base = (long long)r * F;
#pragma unroll
    for (int j = 0; j < F; ++j) H[base + j] = acc[j];
}

// ---------------- XCD-pinned chunked CSR aggregation, broadcast loads --------
// grid.x = 8 * ceil(n/NPB); chunk = blockIdx.x & 7. All TPN lanes of a segment
// load epack[j] at the SAME address (HW broadcast, L1 line holds 8 edges);
// no cross-lane ops. 8-deep unrolled gather+FMA for MLP.
template <int F, int CHW, int TPN>
__global__ __launch_bounds__(BT) void agg_bcast_kernel(const int* __restrict__ rowptr,
                                                       const long long* __restrict__ epack,
                                                       const float* __restrict__ H,
                                                       const float* __restrict__ dis,
                                                       const float* __restrict__ bias,
                                                       float* __restrict__ A, int n) {
    constexpr int NPB = BT / TPN;  // nodes per block
    const int chunk = blockIdx.x & 7;
    const int nblk = blockIdx.x >> 3;
    const int tid = threadIdx.x;
    const int node = nblk * NPB + tid / TPN;
    const int lane = tid & (TPN - 1);
    if (node >= n) return;
    const float* __restrict__ Hc = H + (size_t)chunk * n * CHW;
    const int f = chunk * CHW + lane;
    const bool fv = (lane < CHW) && (f < F);

    float acc = 0.f;
    int j = rowptr[node];
    const int end = rowptr[node + 1];
    for (; j + 8 <= end; j += 8) {
        long long e0 = epack[j + 0];
        long long e1 = epack[j + 1];
        long long e2 = epack[j + 2];
        long long e3 = epack[j + 3];
        long long e4 = epack[j + 4];
        long long e5 = epack[j + 5];
        long long e6 = epack[j + 6];
        long long e7 = epack[j + 7];
        if (fv) {
            float h0 = Hc[(size_t)(int)e0 * CHW + lane];
            float h1 = Hc[(size_t)(int)e1 * CHW + lane];
            float h2 = Hc[(size_t)(int)e2 * CHW + lane];
            float h3 = Hc[(size_t)(int)e3 * CHW + lane];
            float h4 = Hc[(size_t)(int)e4 * CHW + lane];
            float h5 = Hc[(size_t)(int)e5 * CHW + lane];
            float h6 = Hc[(size_t)(int)e6 * CHW + lane];
            float h7 = Hc[(size_t)(int)e7 * CHW + lane];
            acc += __int_as_float((int)(e0 >> 32)) * h0;
            acc += __int_as_float((int)(e1 >> 32)) * h1;
            acc += __int_as_float((int)(e2 >> 32)) * h2;
            acc += __int_as_float((int)(e3 >> 32)) * h3;
            acc += __int_as_float((int)(e4 >> 32)) * h4;
            acc += __int_as_float((int)(e5 >> 32)) * h5;
            acc += __int_as_float((int)(e6 >> 32)) * h6;
            acc += __int_as_float((int)(e7 >> 32)) * h7;
        }
    }
    for (; j < end; ++j) {
        long long ev = epack[j];
        if (fv) acc += __int_as_float((int)(ev >> 32)) * Hc[(size_t)(int)ev * CHW + lane];
    }
    if (fv) {
        float d = dis[node];
        float v = bias[f] + d * d * Hc[(size_t)node * CHW + lane] + acc;
        __builtin_nontemporal_store(v, &A[(size_t)node * F + f]);
    }
}

// simple per-node agg for tiny F (row-major H, fully cache-resident)
template <int F, int TPN>
__global__ __launch_bounds__(BT) void agg_small_kernel(const int* __restrict__ rowptr,
                                                       const long long* __restrict__ epack,
                                                       const float* __restrict__ H,
                                                       const float* __restrict__ dis,
                                                       const float* __restrict__ bias,
                                                       float* __restrict__ A, int n) {
    int gid = blockIdx.x * blockDim.x + threadIdx.x;
    int node = gid / TPN;
    int lane = threadIdx.x & (TPN - 1);
    if (node >= n) return;
    bool active = (lane < F);
    float acc = 0.f;
    int j = rowptr[node];
    const int end = rowptr[node + 1];
    for (; j + 4 <= end; j += 4) {
        long long e0 = epack[j + 0];
        long long e1 = epack[j + 1];
        long long e2 = epack[j + 2];
        long long e3 = epack[j + 3];
        if (active) {
            float h0 = H[(size_t)(int)e0 * F + lane];
            float h1 = H[(size_t)(int)e1 * F + lane];
            float h2 = H[(size_t)(int)e2 * F + lane];
            float h3 = H[(size_t)(int)e3 * F + lane];
            acc += __int_as_float((int)(e0 >> 32)) * h0;
            acc += __int_as_float((int)(e1 >> 32)) * h1;
            acc += __int_as_float((int)(e2 >> 32)) * h2;
            acc += __int_as_float((int)(e3 >> 32)) * h3;
        }
    }
    for (; j < end; ++j) {
        long long ev = epack[j];
        if (active) acc += __int_as_float((int)(ev >> 32)) * H[(size_t)(int)ev * F + lane];
    }
    if (active) {
        float d = dis[node];
        float v = bias[lane] + d * d * H[(size_t)node * F + lane] + acc;
        __builtin_nontemporal_store(v, &A[(size_t)node * F + lane]);
    }
}

// ---------------------------------------------------------------------------
extern "C" void kernel_launch(void* const* d_in, const int* in_sizes, int n_in,
                              void* d_out, int out_size, void* d_ws, size_t ws_size,
                              hipStream_t stream) {
    const float* x  = (const float*)d_in[0];
    const int*   ei = (const int*)d_in[1];
    const float* ew = (const float*)d_in[2];
    const float* W0 = (const float*)d_in[3];
    const float* b0 = (const float*)d_in[4];
    const float* W1 = (const float*)d_in[5];
    const float* b1 = (const float*)d_in[6];
    const float* W2 = (const float*)d_in[7];
    const float* b2 = (const float*)d_in[8];
    const float* W3 = (const float*)d_in[9];
    const float* b3 = (const float*)d_in[10];
    float* out = (float*)d_out;

    const int N = in_sizes[0] / 128;  // 50000
    const int E = in_sizes[1] / 2;    // 800000
    const int* row = ei;
    const int* col = ei + E;

    const int NB = (N + SCAN_B - 1) / SCAN_B;

    // workspace (8B alignment maintained for epack):
    // dis[N] f | rowptr[N+2] i | cursor[N] i | bsums[SCAN_B] i |
    // epack[E] i64 | bufA[N*104] f (chunk-padded H) | bufB[N*100] f
    float* ws = (float*)d_ws;
    float* dis    = ws;
    int*   rowptr = (int*)(dis + N);
    int*   cursor = rowptr + (N + 2);
    int*   bsums  = cursor + N;
    long long* epack = (long long*)(bsums + SCAN_B);
    float* bufA   = (float*)(epack + E);
    float* bufB   = bufA + (size_t)N * 104;

    // ---- CSR + norm precompute ----
    init_kernel<<<(N + BT - 1) / BT, BT, 0, stream>>>(rowptr, dis, N);
    hist_kernel<<<(E + BT - 1) / BT, BT, 0, stream>>>(row, ew, rowptr, dis, E);
    scan1_kernel<<<NB, SCAN_B, 0, stream>>>(rowptr, bsums, dis, N);
    scan2_kernel<<<1, SCAN_B, 0, stream>>>(bsums, NB);
    scan3_kernel<<<(N + BT - 1) / BT, BT, 0, stream>>>(rowptr, bsums, cursor, N, E);
    fill_kernel<<<(E + BT - 1) / BT, BT, 0, stream>>>(row, col, ew, dis, cursor, epack, E);

    // GEMM rows/block: F=100 -> NCG=25, ROWS=40; F=50 -> NCG=13, ROWS=76
    const int g100_blocks = (N + 39) / 40;
    const int g50_blocks  = (N + 75) / 76;

    // agg grids: 8 chunks x node-blocks
    const int agg100_blocks = 8 * ((N + 15) / 16);  // CHW=13, TPN=16, NPB=16
    const int agg50_blocks  = 8 * ((N + 31) / 32);  // CHW=7,  TPN=8,  NPB=32
    const int agg6_blocks   = (N * 8 + BT - 1) / BT;

    // ---- layer 0: x(128) -> 100 ----
    gemm_tile_kernel<128, 100, 13, false><<<g100_blocks, 256, 0, stream>>>(x, W0, bufA, N);
    agg_bcast_kernel<100, 13, 16><<<agg100_blocks, BT, 0, stream>>>(rowptr, epack, bufA, dis, b0, bufB, N);

    // ---- layer 1: 100 -> 100 ----
    gemm_tile_kernel<100, 100, 13, true><<<g100_blocks, 256, 0, stream>>>(bufB, W1, bufA, N);
    agg_bcast_kernel<100, 13, 16><<<agg100_blocks, BT, 0, stream>>>(rowptr, epack, bufA, dis, b1, bufB, N);

    // ---- layer 2: 100 -> 50 ----
    gemm_tile_kernel<100, 50, 7, true><<<g50_blocks, 256, 0, stream>>>(bufB, W2, bufA, N);
    agg_bcast_kernel<50, 7, 8><<<agg50_blocks, BT, 0, stream>>>(rowptr, epack, bufA, dis, b2, bufB, N);

    // ---- layer 3: 50 -> 6 ----
    gemv_rows_kernel<50, 6, true><<<(N + 255) / 256, 256, 0, stream>>>(bufB, W3, bufA, N);
    agg_small_kernel<6, 8><<<agg6_blocks, BT, 0, stream>>>(rowptr, epack, bufA, dis, b3, out, N);
}

// Round 7
// 543.757 us; speedup vs baseline: 1.2753x; 1.1049x over previous
//
#include <hip/hip_runtime.h>

// ---------------------------------------------------------------------------
// GCN forward: CSR aggregation, 4 XCD-pinned feature chunks + float2 lanes.
//   Agg time scales with NCHUNKS*E (issue-bound per edge-chunk: R4/R6 evidence),
//   so use the fewest chunks whose slice still ~fits an XCD L2: 4 chunks,
//   CHW=26 (F=100, 5.2MB slice, chunk=blockIdx.x&3 -> pinned to 2 XCDs).
//   Lanes gather float2 -> 26 features per instruction (TPN=16, 13 active).
//   Edge metadata via same-address broadcast loads (no shfl). 8-deep unroll.
//   A-stores nontemporal. No atomics in hot paths.
// ---------------------------------------------------------------------------

#define BT 256
#define SCAN_B 256

// ---------------- precompute ----------------
__global__ void init_kernel(int* counts, float* wsum, int n) {
    int i = blockIdx.x * blockDim.x + threadIdx.x;
    if (i < n) { counts[i] = 0; wsum[i] = 1.0f; }  // self-loop weight = 1
}

__global__ void hist_kernel(const int* __restrict__ row, const float* __restrict__ w,
                            int* counts, float* wsum, int e) {
    int i = blockIdx.x * blockDim.x + threadIdx.x;
    if (i < e) {
        int r = row[i];
        atomicAdd(&counts[r], 1);
        unsafeAtomicAdd(&wsum[r], w[i]);
    }
}

// exclusive scan of counts (in rowptr[0..n-1]); also wsum -> dis in-place
__global__ void scan1_kernel(int* counts, int* bsums, float* deg, int n) {
    __shared__ int s[SCAN_B];
    int t = threadIdx.x;
    int i = blockIdx.x * SCAN_B + t;
    int v = (i < n) ? counts[i] : 0;
    s[t] = v;
    __syncthreads();
    for (int off = 1; off < SCAN_B; off <<= 1) {
        int x = (t >= off) ? s[t - off] : 0;
        __syncthreads();
        s[t] += x;
        __syncthreads();
    }
    if (i < n) {
        counts[i] = s[t] - v;  // exclusive
        float d = deg[i];
        deg[i] = (d > 0.f) ? rsqrtf(fmaxf(d, 1e-12f)) : 0.f;
    }
    if (t == SCAN_B - 1) bsums[blockIdx.x] = s[t];
}

__global__ void scan2_kernel(int* bsums, int nb) {  // single block, nb <= SCAN_B
    __shared__ int s[SCAN_B];
    int t = threadIdx.x;
    int v = (t < nb) ? bsums[t] : 0;
    s[t] = v;
    __syncthreads();
    for (int off = 1; off < SCAN_B; off <<= 1) {
        int x = (t >= off) ? s[t - off] : 0;
        __syncthreads();
        s[t] += x;
        __syncthreads();
    }
    if (t < nb) bsums[t] = s[t] - v;
}

__global__ void scan3_kernel(int* rowptr, const int* __restrict__ bsums, int* cursor,
                             int n, int e) {
    int i = blockIdx.x * blockDim.x + threadIdx.x;
    if (i < n) {
        int rp = rowptr[i] + bsums[i / SCAN_B];
        rowptr[i] = rp;
        cursor[i] = rp;
    }
    if (i == 0) rowptr[n] = e;
}

__global__ void fill_kernel(const int* __restrict__ row, const int* __restrict__ col,
                            const float* __restrict__ w, const float* __restrict__ dis,
                            int* cursor, long long* __restrict__ epack, int e) {
    int i = blockIdx.x * blockDim.x + threadIdx.x;
    if (i >= e) return;
    int r = row[i], c = col[i];
    float nv = dis[r] * w[i] * dis[c];
    int dst = atomicAdd(&cursor[r], 1);
    long long v = ((long long)__float_as_int(nv) << 32) | (unsigned int)c;
    __builtin_nontemporal_store(v, &epack[dst]);
}

// ---------------- register-tiled GEMM: Hc = chunked(actin(X) @ W) ------------
// X row-major [n,K] (K%4==0); output chunked Hc[c/CHW][n][c%CHW], 4 chunks.
template <int K, int F, int CHW, bool RELU_IN>
__global__ __launch_bounds__(256) void gemm_tile_kernel(const float* __restrict__ X,
                                                        const float* __restrict__ W,
                                                        float* __restrict__ Hc, int n) {
    static_assert(K % 4 == 0, "K must be multiple of 4");
    constexpr int NCG = (F + 3) / 4;
    constexpr int FP = NCG * 4;
    constexpr int RG = 256 / NCG;
    constexpr int ROWS = RG * 4;

    __shared__ float Ws[K * FP];
    const int tid = threadIdx.x;
    for (int i = tid; i < K * FP; i += 256) {
        int k = i / FP, c = i - k * FP;
        Ws[i] = (c < F) ? W[k * F + c] : 0.f;
    }
    __syncthreads();

    const int txc = tid % NCG;
    const int tyr = tid / NCG;
    if (tyr >= RG) return;

    const int r0 = blockIdx.x * ROWS + tyr * 4;
    bool rv[4];
    const float* xrow[4];
#pragma unroll
    for (int i = 0; i < 4; ++i) {
        int r = r0 + i;
        rv[i] = (r < n);
        xrow[i] = X + (long long)(rv[i] ? r : 0) * K;
    }

    float acc[4][4] = {};
    const float* wbase = &Ws[txc * 4];
    for (int k = 0; k < K; k += 4) {
        float4 w0 = *reinterpret_cast<const float4*>(wbase + (k + 0) * FP);
        float4 w1 = *reinterpret_cast<const float4*>(wbase + (k + 1) * FP);
        float4 w2 = *reinterpret_cast<const float4*>(wbase + (k + 2) * FP);
        float4 w3 = *reinterpret_cast<const float4*>(wbase + (k + 3) * FP);
#pragma unroll
        for (int i = 0; i < 4; ++i) {
            float4 x4 = *reinterpret_cast<const float4*>(xrow[i] + k);
            if (RELU_IN) {
                x4.x = fmaxf(x4.x, 0.f); x4.y = fmaxf(x4.y, 0.f);
                x4.z = fmaxf(x4.z, 0.f); x4.w = fmaxf(x4.w, 0.f);
            }
            acc[i][0] += x4.x * w0.x + x4.y * w1.x + x4.z * w2.x + x4.w * w3.x;
            acc[i][1] += x4.x * w0.y + x4.y * w1.y + x4.z * w2.y + x4.w * w3.y;
            acc[i][2] += x4.x * w0.z + x4.y * w1.z + x4.z * w2.z + x4.w * w3.z;
            acc[i][3] += x4.x * w0.w + x4.y * w1.w + x4.z * w2.w + x4.w * w3.w;
        }
    }

#pragma unroll
    for (int i = 0; i < 4; ++i) {
        if (!rv[i]) continue;
        long long r = r0 + i;
#pragma unroll
        for (int j = 0; j < 4; ++j) {
            int c = txc * 4 + j;
            if (c < F) {
                int ch = c / CHW;
                int off = c - ch * CHW;
                Hc[(size_t)ch * n * CHW + r * CHW + off] = acc[i][j];
            }
        }
    }
}

// thread-per-row GEMV for tiny F (layer 3: K=50, F=6), row-major output.
template <int K, int F, bool RELU_IN>
__global__ __launch_bounds__(256) void gemv_rows_kernel(const float* __restrict__ X,
                                                        const float* __restrict__ W,
                                                        float* __restrict__ H, int n) {
    static_assert(K % 2 == 0, "K must be even");
    __shared__ float Ws[K * F];
    const int tid = threadIdx.x;
    for (int i = tid; i < K * F; i += 256) Ws[i] = W[i];
    __syncthreads();
    int r = blockIdx.x * 256 + tid;
    if (r >= n) return;
    float acc[F] = {};
    const float* xp = X + (long long)r * K;
    for (int k = 0; k < K; k += 2) {
        float2 x2 = *reinterpret_cast<const float2*>(xp + k);
        if (RELU_IN) { x2.x = fmaxf(x2.x, 0.f); x2.y = fmaxf(x2.y, 0.f); }
#pragma unroll
        for (int j = 0; j < F; ++j)
            acc[j] += x2.x * Ws[k * F + j] + x2.y * Ws[(k + 1) * F + j];
    }
    long long base = (long long)r * F;
#pragma unroll
    for (int j = 0; j < F; ++j) H[base + j] = acc[j];
}

// ---------------- 4-chunk XCD-pinned CSR aggregation, float2 lanes -----------
// grid.x = 4 * ceil(n/NPB); chunk = blockIdx.x & 3 (pinned to 2 XCDs under
// round-robin dispatch). Lane l of a TPN-segment covers features
// [chunk*CHW + 2l, +1] via one float2 gather. Edge metadata via same-address
// broadcast loads; 8-deep unrolled. Padded tail lanes gather garbage but
// stores are f<F guarded.
template <int F, int CHW, int TPN>
__global__ __launch_bounds__(BT) void agg_f2_kernel(const int* __restrict__ rowptr,
                                                    const long long* __restrict__ epack,
                                                    const float* __restrict__ H,
                                                    const float* __restrict__ dis,
                                                    const float* __restrict__ bias,
                                                    float* __restrict__ A, int n) {
    static_assert(CHW % 2 == 0, "CHW must be even");
    constexpr int NPB = BT / TPN;  // nodes per block
    constexpr int CH2 = CHW / 2;   // float2 per node per chunk
    const int chunk = blockIdx.x & 3;
    const int nblk = blockIdx.x >> 2;
    const int tid = threadIdx.x;
    const int node = nblk * NPB + tid / TPN;
    const int lane = tid & (TPN - 1);
    if (node >= n) return;
    const float2* __restrict__ Hc = (const float2*)(H + (size_t)chunk * n * CHW);
    const int f = chunk * CHW + 2 * lane;
    const bool fv = (lane < CH2);

    float ax = 0.f, ay = 0.f;
    int j = rowptr[node];
    const int end = rowptr[node + 1];
    for (; j + 8 <= end; j += 8) {
        long long e0 = epack[j + 0];
        long long e1 = epack[j + 1];
        long long e2 = epack[j + 2];
        long long e3 = epack[j + 3];
        long long e4 = epack[j + 4];
        long long e5 = epack[j + 5];
        long long e6 = epack[j + 6];
        long long e7 = epack[j + 7];
        if (fv) {
            float2 h0 = Hc[(size_t)(int)e0 * CH2 + lane];
            float2 h1 = Hc[(size_t)(int)e1 * CH2 + lane];
            float2 h2 = Hc[(size_t)(int)e2 * CH2 + lane];
            float2 h3 = Hc[(size_t)(int)e3 * CH2 + lane];
            float2 h4 = Hc[(size_t)(int)e4 * CH2 + lane];
            float2 h5 = Hc[(size_t)(int)e5 * CH2 + lane];
            float2 h6 = Hc[(size_t)(int)e6 * CH2 + lane];
            float2 h7 = Hc[(size_t)(int)e7 * CH2 + lane];
            float n0 = __int_as_float((int)(e0 >> 32));
            float n1 = __int_as_float((int)(e1 >> 32));
            float n2 = __int_as_float((int)(e2 >> 32));
            float n3 = __int_as_float((int)(e3 >> 32));
            float n4 = __int_as_float((int)(e4 >> 32));
            float n5 = __int_as_float((int)(e5 >> 32));
            float n6 = __int_as_float((int)(e6 >> 32));
            float n7 = __int_as_float((int)(e7 >> 32));
            ax += n0 * h0.x; ay += n0 * h0.y;
            ax += n1 * h1.x; ay += n1 * h1.y;
            ax += n2 * h2.x; ay += n2 * h2.y;
            ax += n3 * h3.x; ay += n3 * h3.y;
            ax += n4 * h4.x; ay += n4 * h4.y;
            ax += n5 * h5.x; ay += n5 * h5.y;
            ax += n6 * h6.x; ay += n6 * h6.y;
            ax += n7 * h7.x; ay += n7 * h7.y;
        }
    }
    for (; j < end; ++j) {
        long long ev = epack[j];
        if (fv) {
            float2 h = Hc[(size_t)(int)ev * CH2 + lane];
            float nv = __int_as_float((int)(ev >> 32));
            ax += nv * h.x; ay += nv * h.y;
        }
    }
    if (fv) {
        float d = dis[node];
        float d2 = d * d;
        float2 hs = Hc[(size_t)node * CH2 + lane];
        if (f < F) {
            float v = bias[f] + d2 * hs.x + ax;
            __builtin_nontemporal_store(v, &A[(size_t)node * F + f]);
        }
        if (f + 1 < F) {
            float v = bias[f + 1] + d2 * hs.y + ay;
            __builtin_nontemporal_store(v, &A[(size_t)node * F + f + 1]);
        }
    }
}

// simple per-node agg for tiny F (row-major H, fully cache-resident)
template <int F, int TPN>
__global__ __launch_bounds__(BT) void agg_small_kernel(const int* __restrict__ rowptr,
                                                       const long long* __restrict__ epack,
                                                       const float* __restrict__ H,
                                                       const float* __restrict__ dis,
                                                       const float* __restrict__ bias,
                                                       float* __restrict__ A, int n) {
    int gid = blockIdx.x * blockDim.x + threadIdx.x;
    int node = gid / TPN;
    int lane = threadIdx.x & (TPN - 1);
    if (node >= n) return;
    bool active = (lane < F);
    float acc = 0.f;
    int j = rowptr[node];
    const int end = rowptr[node + 1];
    for (; j + 4 <= end; j += 4) {
        long long e0 = epack[j + 0];
        long long e1 = epack[j + 1];
        long long e2 = epack[j + 2];
        long long e3 = epack[j + 3];
        if (active) {
            float h0 = H[(size_t)(int)e0 * F + lane];
            float h1 = H[(size_t)(int)e1 * F + lane];
            float h2 = H[(size_t)(int)e2 * F + lane];
            float h3 = H[(size_t)(int)e3 * F + lane];
            acc += __int_as_float((int)(e0 >> 32)) * h0;
            acc += __int_as_float((int)(e1 >> 32)) * h1;
            acc += __int_as_float((int)(e2 >> 32)) * h2;
            acc += __int_as_float((int)(e3 >> 32)) * h3;
        }
    }
    for (; j < end; ++j) {
        long long ev = epack[j];
        if (active) acc += __int_as_float((int)(ev >> 32)) * H[(size_t)(int)ev * F + lane];
    }
    if (active) {
        float d = dis[node];
        float v = bias[lane] + d * d * H[(size_t)node * F + lane] + acc;
        __builtin_nontemporal_store(v, &A[(size_t)node * F + lane]);
    }
}

// ---------------------------------------------------------------------------
extern "C" void kernel_launch(void* const* d_in, const int* in_sizes, int n_in,
                              void* d_out, int out_size, void* d_ws, size_t ws_size,
                              hipStream_t stream) {
    const float* x  = (const float*)d_in[0];
    const int*   ei = (const int*)d_in[1];
    const float* ew = (const float*)d_in[2];
    const float* W0 = (const float*)d_in[3];
    const float* b0 = (const float*)d_in[4];
    const float* W1 = (const float*)d_in[5];
    const float* b1 = (const float*)d_in[6];
    const float* W2 = (const float*)d_in[7];
    const float* b2 = (const float*)d_in[8];
    const float* W3 = (const float*)d_in[9];
    const float* b3 = (const float*)d_in[10];
    float* out = (float*)d_out;

    const int N = in_sizes[0] / 128;  // 50000
    const int E = in_sizes[1] / 2;    // 800000
    const int* row = ei;
    const int* col = ei + E;

    const int NB = (N + SCAN_B - 1) / SCAN_B;

    // workspace (8B alignment maintained for epack):
    // dis[N] f | rowptr[N+2] i | cursor[N] i | bsums[SCAN_B] i |
    // epack[E] i64 | bufA[N*104] f (chunk-padded H, 4x26) | bufB[N*100] f
    float* ws = (float*)d_ws;
    float* dis    = ws;
    int*   rowptr = (int*)(dis + N);
    int*   cursor = rowptr + (N + 2);
    int*   bsums  = cursor + N;
    long long* epack = (long long*)(bsums + SCAN_B);
    float* bufA   = (float*)(epack + E);
    float* bufB   = bufA + (size_t)N * 104;

    // ---- CSR + norm precompute ----
    init_kernel<<<(N + BT - 1) / BT, BT, 0, stream>>>(rowptr, dis, N);
    hist_kernel<<<(E + BT - 1) / BT, BT, 0, stream>>>(row, ew, rowptr, dis, E);
    scan1_kernel<<<NB, SCAN_B, 0, stream>>>(rowptr, bsums, dis, N);
    scan2_kernel<<<1, SCAN_B, 0, stream>>>(bsums, NB);
    scan3_kernel<<<(N + BT - 1) / BT, BT, 0, stream>>>(rowptr, bsums, cursor, N, E);
    fill_kernel<<<(E + BT - 1) / BT, BT, 0, stream>>>(row, col, ew, dis, cursor, epack, E);

    // GEMM rows/block: F=100 -> NCG=25, ROWS=40; F=50 -> NCG=13, ROWS=76
    const int g100_blocks = (N + 39) / 40;
    const int g50_blocks  = (N + 75) / 76;

    // agg grids: 4 chunks x node-blocks
    const int agg100_blocks = 4 * ((N + 15) / 16);  // CHW=26, TPN=16, NPB=16
    const int agg50_blocks  = 4 * ((N + 31) / 32);  // CHW=14, TPN=8,  NPB=32
    const int agg6_blocks   = (N * 8 + BT - 1) / BT;

    // ---- layer 0: x(128) -> 100 ----
    gemm_tile_kernel<128, 100, 26, false><<<g100_blocks, 256, 0, stream>>>(x, W0, bufA, N);
    agg_f2_kernel<100, 26, 16><<<agg100_blocks, BT, 0, stream>>>(rowptr, epack, bufA, dis, b0, bufB, N);

    // ---- layer 1: 100 -> 100 ----
    gemm_tile_kernel<100, 100, 26, true><<<g100_blocks, 256, 0, stream>>>(bufB, W1, bufA, N);
    agg_f2_kernel<100, 26, 16><<<agg100_blocks, BT, 0, stream>>>(rowptr, epack, bufA, dis, b1, bufB, N);

    // ---- layer 2: 100 -> 50 ----
    gemm_tile_kernel<100, 50, 14, true><<<g50_blocks, 256, 0, stream>>>(bufB, W2, bufA, N);
    agg_f2_kernel<50, 14, 8><<<agg50_blocks, BT, 0, stream>>>(rowptr, epack, bufA, dis, b2, bufB, N);

    // ---- layer 3: 50 -> 6 ----
    gemv_rows_kernel<50, 6, true><<<(N + 255) / 256, 256, 0, stream>>>(bufB, W3, bufA, N);
    agg_small_kernel<6, 8><<<agg6_blocks, BT, 0, stream>>>(rowptr, epack, bufA, dis, b3, out, N);
}